// Round 20
// baseline (56.916 us; speedup 1.0000x reference)
//
#include <hip/hip_runtime.h>
#include <hip/hip_bf16.h>
#include <math.h>

#define IN_C 31
#define OUT_C 31
#define NPIX 16384
#define UW_OFF 7688
#define RW_OFF 8649
#define PART_OFF (640 * 1024)  // ws: 31 chunks (620 KB) + pad, then partials
#define CHUNK_BYTES 20480      // 20 KB of packed W-fragments per input channel i

typedef __attribute__((ext_vector_type(8))) _Float16 f16x8;
typedef __attribute__((ext_vector_type(4))) float f32x4;

__device__ inline short f2h(float f) {            // prep kernel only (cold): RNE
    union { _Float16 h; short s; } cv;
    cv.h = (_Float16)f;
    return cv.s;
}

// ---------------- prep: pack generator weights into MFMA fragment chunks ------
// ws layout: for i in [0,31): 20 chunks of 1 KB (20 KB per i, 620 KB total):
//   pairs 0..7 : spline W, chunk = kc*2 + ot  (kc in [0,8), ot in {0,1})
//   pair 8 (chunks 16,17) : uw W;  pair 9 (chunks 18,19) : rw W   (FP16)
// Chunk lane l, elem j = W[o = ot*16+(l&15)][c = (l>>4)*8+j]; c==31 carries the
// bias (x~[31]=1), o==31 rows are zero. Verified as A-operand in R19 (passed).
__global__ __launch_bounds__(64) void kan_prep_kernel(
    const float* __restrict__ gw, const float* __restrict__ gb,
    unsigned short* __restrict__ ws)
{
    const int blk = blockIdx.x;          // 31*20 = 620
    const int i   = blk / 20;
    const int ch  = blk % 20;
    const int l   = threadIdx.x;
    const int col = l & 15;
    const int krow = l >> 4;
    const int o = (ch & 1) * 16 + col;

    int p;
    if (ch < 16)      p = (i * 31 + o) * 8 + (ch >> 1);
    else if (ch < 18) p = UW_OFF + i * 31 + o;
    else              p = RW_OFF + i * 31 + o;

    short v8[8];
#pragma unroll
    for (int j = 0; j < 8; ++j) {
        const int c = krow * 8 + j;
        float v = 0.f;
        if (o < OUT_C) v = (c < IN_C) ? gw[p * 31 + c] : gb[p];
        v8[j] = f2h(v);
    }
    *(f16x8*)&ws[(blk * 64 + l) * 8] = *(f16x8*)v8;
}

// ---------------- main: NO weight LDS -- stream W fragments from L2 -----------
// Block = 128 thr = 2 waves x 32 px = 64 px. Each wave fully independent:
// ZERO barriers in the i-loop (no staging, no convoy -- the block-lockstep +
// LDS-read pipe that capped rounds 7-19). W fragments are buffer_loads from
// L2 (620 KB working set, hot in every XCD L2; total redundant traffic
// ~317 MB ~ 9.5us at L2 BW, overlapped). Swapped operands (R19-verified):
// W = A from memory, ax = B loop-invariant register; every MFMA input is a
// load result or stable reg -- no VALU->MFMA dependency. Each W fragment
// feeds BOTH px-tiles (32 px/wave halves traffic vs R19's 16).
// LDS = 8.4 KB (output gather only) -> 8 blocks/CU = 16 waves/CU.
// Grid = (256 ptiles, 8 igroups) = 2048 blocks. y=0 -> out, y>0 -> partials.
__global__ __launch_bounds__(128) void kan_mfma16_kernel(
    const float* __restrict__ x,               // (31, 16384)
    const unsigned char* __restrict__ wsw,     // packed W fragments (bytes)
    float* __restrict__ parts,                 // (nsplit-1) x (31,16384)
    float* __restrict__ out,                   // (31, 16384)
    int nsplit)
{
    const int t = threadIdx.x;
    const int l = t & 63;
    const int w = t >> 6;                      // 0..1
    const int pix0 = blockIdx.x * 64;
    const int csize = (IN_C + nsplit - 1) / nsplit;   // 4 at nsplit=8
    const int ibase = blockIdx.y * csize;
    const int iend = min(ibase + csize, IN_C);

    __shared__ float yb[64 * 33];              // 8.4 KB, gather only

    const int pr0 = pix0 + w * 32 + (l & 15);  // px-tile-0 pixel row

    // x~ B-fragments (f16, once per wave), both px-tiles; lane holds
    // col px = l&15, k-slots c = (l>>4)*8 + j.
    f16x8 ax0, ax1;
    {
        const int cb = (l >> 4) * 8;
#pragma unroll
        for (int j = 0; j < 8; ++j) {
            const int c = cb + j;
            ax0[j] = (_Float16)((c < IN_C) ? x[c * NPIX + pr0] : 1.0f);
            ax1[j] = (_Float16)((c < IN_C) ? x[c * NPIX + pr0 + 16] : 1.0f);
        }
    }

    f32x4 Y[2][2];   // [ot][pxt]; C layout: row = o, col = px
#pragma unroll
    for (int ot = 0; ot < 2; ++ot)
#pragma unroll
        for (int pt = 0; pt < 2; ++pt) Y[ot][pt] = (f32x4){0.f, 0.f, 0.f, 0.f};

    const f32x4 z = (f32x4){0.f, 0.f, 0.f, 0.f};

#pragma unroll 1
    for (int i = ibase; i < iend; ++i) {
        const f16x8* wg = (const f16x8*)(wsw + (size_t)i * CHUNK_BYTES);

        const float xv0 = x[i * NPIX + pr0];
        const float xv1 = x[i * NPIX + pr0 + 16];

        // basis (uniform cardinal cubic) + silu for both px-tiles (f32)
        float bas0[8], bas1[8], sil0, sil1;
#pragma unroll
        for (int s = 0; s < 2; ++s) {
            const float xv = (s == 0) ? xv0 : xv1;
            const float tb = (xv + 2.2f) * 2.5f;
            const float jf = floorf(tb);
            const float u  = tb - jf;
            const int  jj  = (int)jf;
            const float u2 = u * u, u3 = u2 * u;
            const float b0v = u3 * (1.f / 6.f);
            const float b1v = (-3.f * u3 + 3.f * u2 + 3.f * u + 1.f) * (1.f / 6.f);
            const float b2v = (3.f * u3 - 6.f * u2 + 4.f) * (1.f / 6.f);
            const float omu = 1.f - u;
            const float b3v = omu * omu * omu * (1.f / 6.f);
#pragma unroll
            for (int m = 0; m < 8; ++m) {
                const int d = jj - m;
                const float bv = (d == 0) ? b0v : (d == 1) ? b1v : (d == 2) ? b2v
                               : (d == 3) ? b3v : 0.f;
                if (s == 0) bas0[m] = bv; else bas1[m] = bv;
            }
            const float sv = xv / (1.f + __expf(-xv));
            if (s == 0) sil0 = sv; else sil1 = sv;
        }

        f32x4 SP[2][2];
#pragma unroll
        for (int ot = 0; ot < 2; ++ot)
#pragma unroll
            for (int pt = 0; pt < 2; ++pt) SP[ot][pt] = z;

        // spline: 32 independent zero-C MFMAs fed by global loads (L2-hot);
        // each fragment pair feeds both px-tiles. Fold with lane-local bas.
#pragma unroll
        for (int p = 0; p < 8; ++p) {
            const f16x8 a0 = wg[(p * 2 + 0) * 64 + l];
            const f16x8 a1 = wg[(p * 2 + 1) * 64 + l];
            const f32x4 T00 = __builtin_amdgcn_mfma_f32_16x16x32_f16(a0, ax0, z, 0, 0, 0);
            const f32x4 T01 = __builtin_amdgcn_mfma_f32_16x16x32_f16(a0, ax1, z, 0, 0, 0);
            const f32x4 T10 = __builtin_amdgcn_mfma_f32_16x16x32_f16(a1, ax0, z, 0, 0, 0);
            const f32x4 T11 = __builtin_amdgcn_mfma_f32_16x16x32_f16(a1, ax1, z, 0, 0, 0);
#pragma unroll
            for (int r = 0; r < 4; ++r) {
                SP[0][0][r] = fmaf(bas0[p], T00[r], SP[0][0][r]);
                SP[0][1][r] = fmaf(bas1[p], T01[r], SP[0][1][r]);
                SP[1][0][r] = fmaf(bas0[p], T10[r], SP[1][0][r]);
                SP[1][1][r] = fmaf(bas1[p], T11[r], SP[1][1][r]);
            }
        }
        // uw + rw (zero-C transients), fold: Y += UW*SP + sil*R
        {
            const f16x8 u0 = wg[16 * 64 + l];
            const f16x8 u1 = wg[17 * 64 + l];
            const f16x8 r0 = wg[18 * 64 + l];
            const f16x8 r1 = wg[19 * 64 + l];
#pragma unroll
            for (int pt = 0; pt < 2; ++pt) {
                const f16x8 axp = (pt == 0) ? ax0 : ax1;
                const float sil = (pt == 0) ? sil0 : sil1;
                const f32x4 UW0 = __builtin_amdgcn_mfma_f32_16x16x32_f16(u0, axp, z, 0, 0, 0);
                const f32x4 UW1 = __builtin_amdgcn_mfma_f32_16x16x32_f16(u1, axp, z, 0, 0, 0);
                const f32x4 R0  = __builtin_amdgcn_mfma_f32_16x16x32_f16(r0, axp, z, 0, 0, 0);
                const f32x4 R1  = __builtin_amdgcn_mfma_f32_16x16x32_f16(r1, axp, z, 0, 0, 0);
#pragma unroll
                for (int r = 0; r < 4; ++r) {
                    Y[0][pt][r] = fmaf(UW0[r], SP[0][pt][r], fmaf(sil, R0[r], Y[0][pt][r]));
                    Y[1][pt][r] = fmaf(UW1[r], SP[1][pt][r], fmaf(sil, R1[r], Y[1][pt][r]));
                }
            }
        }
    }

    // ---- gather (swapped C layout: row = o = ot*16+(l>>4)*4+r, col = px) ----
#pragma unroll
    for (int ot = 0; ot < 2; ++ot)
#pragma unroll
        for (int pt = 0; pt < 2; ++pt)
#pragma unroll
            for (int r = 0; r < 4; ++r) {
                const int o = ot * 16 + (l >> 4) * 4 + r;
                const int p = w * 32 + pt * 16 + (l & 15);
                if (o < OUT_C) yb[p * 33 + o] = Y[ot][pt][r];
            }
    __syncthreads();

    float* dst = (blockIdx.y == 0) ? out
               : (parts + (size_t)(blockIdx.y - 1) * OUT_C * NPIX);
    for (int idx = t; idx < 64 * OUT_C; idx += 128) {
        const int n = idx & 63, o = idx >> 6;
        dst[o * NPIX + pix0 + n] = yb[n * 33 + o];
    }
}

// ---------------- combine: out += sum of npart partials (vectorized) ----------
__global__ __launch_bounds__(256) void kan_combine_kernel(
    float* __restrict__ out, const float* __restrict__ parts, int npart)
{
    const int e = blockIdx.x * 256 + threadIdx.x;   // float4 index
    const int nv = (OUT_C * NPIX) / 4;
    if (e < nv) {
        f32x4 a = ((const f32x4*)out)[e];
        for (int j = 0; j < npart; ++j)
            a += ((const f32x4*)parts)[e + (size_t)j * nv];
        ((f32x4*)out)[e] = a;
    }
}

extern "C" void kernel_launch(void* const* d_in, const int* in_sizes, int n_in,
                              void* d_out, int out_size, void* d_ws, size_t ws_size,
                              hipStream_t stream) {
    const float* x  = (const float*)d_in[0];
    const float* gw = (const float*)d_in[1];
    const float* gb = (const float*)d_in[2];
    float* out = (float*)d_out;
    unsigned short* ws = (unsigned short*)d_ws;
    float* parts = (float*)((char*)d_ws + PART_OFF);

    // 8-way i-split: 7 f32 partials (14.3 MB). Deterministic fallback.
    const size_t part_bytes = (size_t)OUT_C * NPIX * 4;
    int nsplit = 8;
    if (ws_size < PART_OFF + 7 * part_bytes) nsplit = 4;
    if (ws_size < PART_OFF + 3 * part_bytes) nsplit = 2;

    hipLaunchKernelGGL(kan_prep_kernel, dim3(620), dim3(64), 0, stream, gw, gb, ws);
    hipLaunchKernelGGL(kan_mfma16_kernel, dim3(NPIX / 64, nsplit), dim3(128), 0, stream,
                       x, (const unsigned char*)d_ws, parts, out, nsplit);
    const int nv = (OUT_C * NPIX) / 4;                 // 126976
    hipLaunchKernelGGL(kan_combine_kernel, dim3((nv + 255) / 256), dim3(256), 0, stream,
                       out, parts, nsplit - 1);
}

// Round 21
// 39.587 us; speedup vs baseline: 1.4378x; 1.4378x over previous
//
#include <hip/hip_runtime.h>
#include <hip/hip_bf16.h>
#include <math.h>

#define IN_C 31
#define OUT_C 31
#define NPIX 16384
#define UW_OFF 7688
#define RW_OFF 8649
#define PART_OFF (640 * 1024)  // ws byte offset of partial-Y buffers (weights use 620 KB)
#define CHUNK_BYTES 20480      // 20 KB of packed B-fragments per input channel i

typedef __attribute__((ext_vector_type(8))) _Float16 f16x8;
typedef __attribute__((ext_vector_type(4))) float f32x4;

__device__ inline short f2h(float f) {            // prep kernel only (cold): RNE
    union { _Float16 h; short s; } cv;
    cv.h = (_Float16)f;
    return cv.s;
}

// ---------------- prep: pack generator weights into MFMA B-fragment chunks ----
// ws layout: for i in [0,31): 20 chunks of 1 KB (20 KB per i, 620 KB total):
//   pairs 0..7 : spline B, chunk = kc*2 + nt  (kc in [0,8), nt in {0,1})
//   pair 8 (chunks 16,17) : uw B;  pair 9 (chunks 18,19) : rw B   (FP16)
__global__ __launch_bounds__(64) void kan_prep_kernel(
    const float* __restrict__ gw, const float* __restrict__ gb,
    unsigned short* __restrict__ ws)
{
    const int blk = blockIdx.x;          // 31*20 = 620
    const int i   = blk / 20;
    const int ch  = blk % 20;
    const int l   = threadIdx.x;
    const int col = l & 15;
    const int krow = l >> 4;
    const int o = (ch & 1) * 16 + col;

    int p;
    if (ch < 16)      p = (i * 31 + o) * 8 + (ch >> 1);
    else if (ch < 18) p = UW_OFF + i * 31 + o;
    else              p = RW_OFF + i * 31 + o;

    short v8[8];
#pragma unroll
    for (int j = 0; j < 8; ++j) {
        const int c = krow * 8 + j;
        float v = 0.f;
        if (o < OUT_C) v = (c < IN_C) ? gw[p * 31 + c] : gb[p];
        v8[j] = f2h(v);
    }
    *(f16x8*)&ws[(blk * 64 + l) * 8] = *(f16x8*)v8;
}

// Stage one i's 20 KB chunk into LDS via async global->LDS DMA, 512 threads:
// 1280 16B slots: 2 full passes (1024) + waves 0..3 take the tail (256).
__device__ __forceinline__ void stage_i(const unsigned char* wsrc,
                                        unsigned char* ldst, int t) {
#pragma unroll
    for (int k = 0; k < 2; ++k) {
        const int off = (k * 512 + t) * 16;
        __builtin_amdgcn_global_load_lds(
            (const __attribute__((address_space(1))) unsigned int*)(wsrc + off),
            (__attribute__((address_space(3))) unsigned int*)(ldst + off),
            16, 0, 0);
    }
    if (t < 256) {                       // wave-uniform (waves 0..3)
        const int off = (1024 + t) * 16;
        __builtin_amdgcn_global_load_lds(
            (const __attribute__((address_space(1))) unsigned int*)(wsrc + off),
            (__attribute__((address_space(3))) unsigned int*)(ldst + off),
            16, 0, 0);
    }
}

// ---------------- main: TWO interleaved i-bodies per wave (ILP) ---------------
// Block = 512 thr = 8 waves x 16 px = 128 px; all waves share the SAME i-pair.
// Per pair (i0,i1): stage next pair into the other 2 of 4 LDS buffers ->
// basis/silu for both i -> p-loop 0..9 issuing BOTH i's ds_reads + MFMAs
// (independent SP/UW accumulator sets = 2 independent dep-chains per wave) ->
// fold -> ONE barrier per 2 i's. LDS = 4x20KB = 80 KB.
// gridDim.y=4 splits i (8/8/8/7); y=0 -> out, y>0 -> partials; combine sums.
// [FINAL: best-measured config of the session -- 39.5 us total.]
__global__ __launch_bounds__(512) void kan_mfma11_kernel(
    const float* __restrict__ x,               // (31, 16384)
    const unsigned char* __restrict__ wsw,     // packed B fragments (bytes)
    float* __restrict__ parts,                 // (nsplit-1) x (31,16384)
    float* __restrict__ out,                   // (31, 16384)
    int nsplit)
{
    const int t = threadIdx.x;
    const int l = t & 63;
    const int w = t >> 6;                      // 0..7
    const int pix0 = blockIdx.x * 128;
    const int csize = (IN_C + nsplit - 1) / nsplit;
    const int ibase = blockIdx.y * csize;
    const int iend = min(ibase + csize, IN_C);

    __shared__ __align__(16) unsigned char bufs[4][CHUNK_BYTES]; // 80 KB, reused for Y

    const int n0 = w * 16;
    const int prow = pix0 + n0 + (l & 15);     // this lane's pixel row

    // x~ fragment (f16, once per block): lane holds c = (l>>4)*8 + j
    f16x8 xv8f;
    {
        const int cb = (l >> 4) * 8;
#pragma unroll
        for (int j = 0; j < 8; ++j) {
            const int c = cb + j;
            const float v = (c < IN_C) ? x[c * NPIX + prow] : 1.0f;  // x~[31]=1
            xv8f[j] = (_Float16)v;
        }
    }

    f32x4 Y[2];
    Y[0] = (f32x4){0.f, 0.f, 0.f, 0.f};
    Y[1] = (f32x4){0.f, 0.f, 0.f, 0.f};

    // prologue: stage first i-pair
    stage_i(wsw + (size_t)ibase * CHUNK_BYTES, bufs[0], t);
    if (ibase + 1 < iend)
        stage_i(wsw + (size_t)(ibase + 1) * CHUNK_BYTES, bufs[1], t);
    __syncthreads();

    const int npairs = (iend - ibase + 1) >> 1;

#pragma unroll 1
    for (int tp = 0; tp < npairs; ++tp) {
        const int i0 = ibase + 2 * tp;
        const bool has1 = (i0 + 1) < iend;     // wave-uniform

        // stage next pair into the other buffer half
        if (tp + 1 < npairs) {
            const int nx = i0 + 2;
            unsigned char* d0 = bufs[2 * ((tp + 1) & 1)];
            stage_i(wsw + (size_t)nx * CHUNK_BYTES, d0, t);
            if (nx + 1 < iend)
                stage_i(wsw + (size_t)(nx + 1) * CHUNK_BYTES, d0 + CHUNK_BYTES, t);
        }

        // per-i x values (L2-hit; latency overlaps basis/silu below)
        const float xa = x[i0 * NPIX + prow];
        const float xb = has1 ? x[(i0 + 1) * NPIX + prow] : 0.f;

        // basis + silu for BOTH i (f32 VALU, single f16 casts)
        _Float16 basA[8], basB[8];
        f16x8 arwA, arwB;
#pragma unroll
        for (int s = 0; s < 2; ++s) {
            const float xv = (s == 0) ? xa : xb;
            const float tb = (xv + 2.2f) * 2.5f;
            const float jf = floorf(tb);
            const float u  = tb - jf;
            const int  jj  = (int)jf;
            const float u2 = u * u, u3 = u2 * u;
            const float b0v = u3 * (1.f / 6.f);
            const float b1v = (-3.f * u3 + 3.f * u2 + 3.f * u + 1.f) * (1.f / 6.f);
            const float b2v = (3.f * u3 - 6.f * u2 + 4.f) * (1.f / 6.f);
            const float omu = 1.f - u;
            const float b3v = omu * omu * omu * (1.f / 6.f);
#pragma unroll
            for (int m = 0; m < 8; ++m) {
                const int d = jj - m;
                const float bv = (d == 0) ? b0v : (d == 1) ? b1v : (d == 2) ? b2v
                               : (d == 3) ? b3v : 0.f;
                if (s == 0) basA[m] = (_Float16)bv; else basB[m] = (_Float16)bv;
            }
            const float sil = xv / (1.f + __expf(-xv));
            if (s == 0) arwA = xv8f * (_Float16)sil;
            else        arwB = xv8f * (_Float16)sil;
        }

        const unsigned char* wbA = bufs[2 * (tp & 1)];
        const unsigned char* wbB = wbA + CHUNK_BYTES;

        f32x4 SPA[2], UWA[2], SPB[2], UWB[2];
#pragma unroll
        for (int nt = 0; nt < 2; ++nt) {
            SPA[nt] = (f32x4){0.f, 0.f, 0.f, 0.f};
            UWA[nt] = (f32x4){0.f, 0.f, 0.f, 0.f};
            SPB[nt] = (f32x4){0.f, 0.f, 0.f, 0.f};
            UWB[nt] = (f32x4){0.f, 0.f, 0.f, 0.f};
        }

        // 10 pairs; both i-streams issued together (independent dep chains)
#pragma unroll
        for (int p = 0; p < 10; ++p) {
            const f16x8 a0 = *(const f16x8*)(wbA + ((p * 2 + 0) * 64 + l) * 16);
            const f16x8 a1 = *(const f16x8*)(wbA + ((p * 2 + 1) * 64 + l) * 16);
            const f16x8 c0 = *(const f16x8*)(wbB + ((p * 2 + 0) * 64 + l) * 16);
            const f16x8 c1 = *(const f16x8*)(wbB + ((p * 2 + 1) * 64 + l) * 16);
            if (p < 8) {
                const f16x8 afA = xv8f * basA[p];      // 4 v_pk_mul_f16
                SPA[0] = __builtin_amdgcn_mfma_f32_16x16x32_f16(afA, a0, SPA[0], 0, 0, 0);
                SPA[1] = __builtin_amdgcn_mfma_f32_16x16x32_f16(afA, a1, SPA[1], 0, 0, 0);
                if (has1) {
                    const f16x8 afB = xv8f * basB[p];
                    SPB[0] = __builtin_amdgcn_mfma_f32_16x16x32_f16(afB, c0, SPB[0], 0, 0, 0);
                    SPB[1] = __builtin_amdgcn_mfma_f32_16x16x32_f16(afB, c1, SPB[1], 0, 0, 0);
                }
            } else if (p == 8) {
                UWA[0] = __builtin_amdgcn_mfma_f32_16x16x32_f16(xv8f, a0, UWA[0], 0, 0, 0);
                UWA[1] = __builtin_amdgcn_mfma_f32_16x16x32_f16(xv8f, a1, UWA[1], 0, 0, 0);
                if (has1) {
                    UWB[0] = __builtin_amdgcn_mfma_f32_16x16x32_f16(xv8f, c0, UWB[0], 0, 0, 0);
                    UWB[1] = __builtin_amdgcn_mfma_f32_16x16x32_f16(xv8f, c1, UWB[1], 0, 0, 0);
                }
            } else {
                Y[0] = __builtin_amdgcn_mfma_f32_16x16x32_f16(arwA, a0, Y[0], 0, 0, 0);
                Y[1] = __builtin_amdgcn_mfma_f32_16x16x32_f16(arwA, a1, Y[1], 0, 0, 0);
                if (has1) {
                    Y[0] = __builtin_amdgcn_mfma_f32_16x16x32_f16(arwB, c0, Y[0], 0, 0, 0);
                    Y[1] = __builtin_amdgcn_mfma_f32_16x16x32_f16(arwB, c1, Y[1], 0, 0, 0);
                }
            }
        }

        // fold: Y += UW * SP for both i (identical fragment layout)
#pragma unroll
        for (int nt = 0; nt < 2; ++nt)
#pragma unroll
            for (int r = 0; r < 4; ++r) {
                Y[nt][r] = fmaf(UWA[nt][r], SPA[nt][r], Y[nt][r]);
                if (has1) Y[nt][r] = fmaf(UWB[nt][r], SPB[nt][r], Y[nt][r]);
            }

        // ONE barrier per 2 i's: drains vmcnt (next pair staged) + ordering
        __syncthreads();
    }

    // ---- gather Y into bufs (free now) for coalesced store ----
    float* yb = (float*)bufs;   // 128*33 floats = 16.9 KB << 80 KB
#pragma unroll
    for (int nt = 0; nt < 2; ++nt)
#pragma unroll
        for (int r = 0; r < 4; ++r) {
            const int p = n0 + (l >> 4) * 4 + r;
            const int o = nt * 16 + (l & 15);
            if (o < OUT_C) yb[p * 33 + o] = Y[nt][r];
        }
    __syncthreads();

    float* dst = (blockIdx.y == 0) ? out
               : (parts + (size_t)(blockIdx.y - 1) * OUT_C * NPIX);
    for (int idx = t; idx < 128 * OUT_C; idx += 512) {
        const int n = idx & 127, o = idx >> 7;
        dst[o * NPIX + pix0 + n] = yb[n * 33 + o];
    }
}

// ---------------- combine: out += sum of npart partials (vectorized) ----------
__global__ __launch_bounds__(256) void kan_combine_kernel(
    float* __restrict__ out, const float* __restrict__ parts, int npart)
{
    const int e = blockIdx.x * 256 + threadIdx.x;   // float4 index
    const int nv = (OUT_C * NPIX) / 4;
    if (e < nv) {
        f32x4 a = ((const f32x4*)out)[e];
        for (int j = 0; j < npart; ++j)
            a += ((const f32x4*)parts)[e + (size_t)j * nv];
        ((f32x4*)out)[e] = a;
    }
}

extern "C" void kernel_launch(void* const* d_in, const int* in_sizes, int n_in,
                              void* d_out, int out_size, void* d_ws, size_t ws_size,
                              hipStream_t stream) {
    const float* x  = (const float*)d_in[0];
    const float* gw = (const float*)d_in[1];
    const float* gb = (const float*)d_in[2];
    float* out = (float*)d_out;
    unsigned short* ws = (unsigned short*)d_ws;
    float* parts = (float*)((char*)d_ws + PART_OFF);

    // 4-way i-split: 3 f32 partials (6.1 MB). Deterministic fallback.
    const size_t part_bytes = (size_t)OUT_C * NPIX * 4;
    int nsplit = 4;
    if (ws_size < PART_OFF + 3 * part_bytes) nsplit = 2;

    hipLaunchKernelGGL(kan_prep_kernel, dim3(620), dim3(64), 0, stream, gw, gb, ws);
    hipLaunchKernelGGL(kan_mfma11_kernel, dim3(NPIX / 128, nsplit), dim3(512), 0, stream,
                       x, (const unsigned char*)d_ws, parts, out, nsplit);
    const int nv = (OUT_C * NPIX) / 4;                 // 126976
    hipLaunchKernelGGL(kan_combine_kernel, dim3((nv + 255) / 256), dim3(256), 0, stream,
                       out, parts, nsplit - 1);
}